// Round 10
// baseline (25.253 us; speedup 1.0000x reference)
//
#include <hip/hip_runtime.h>
#include <math.h>

#define KACC 10
#define ROWS 12    // rows scanned up front (P(col needs more) ~ 0.12%)
#define SC   64    // columns per scan block; 12 waves x 64 lanes = 768 threads

__global__ __launch_bounds__(768)
void sss_kernel(const float* __restrict__ Z, const float* __restrict__ U,
                const float* __restrict__ uu, const float* __restrict__ ga,
                const float* __restrict__ la, float* __restrict__ out,
                int P, int B, int nbScan, int perK, int vec4)
{
#pragma clang fp contract(off)
    const size_t KP = (size_t)KACC * (size_t)P;
    float* o_z        = out;
    float* o_zmean    = out + KP;
    float* o_theta    = out + KP + (size_t)P;
    float* o_alpha    = out + 2 * KP + (size_t)P;
    float* o_logalpha = out + 2 * KP + 2 * (size_t)P;

    const int bid = blockIdx.x;

    if (bid < nbScan) {
        // -------- SCAN ROLE: 1 row/thread, 12 waves, ballot masks --------
        __shared__ float s_val[ROWS][SC];            // 3 KiB candidate values
        __shared__ unsigned long long s_rm[ROWS];    // per-row 64-col accept mask

        const int t    = threadIdx.x;
        const int lane = t & 63;
        const int grp  = t >> 6;                     // 0..11 = row (phase 1)
        const int col  = bid * SC + lane;
        const bool cok = (col < P);

        const float g = cok ? ga[col] : 1.0f;        // 12x redundant, L1-hit
        const float alpha = fmaxf(g, 0.0f) + 1.0f;   // relu + 1
        const float d     = alpha - (1.0f / 3.0f);
        const float c     = 1.0f / sqrtf(9.0f * d);
        const float ni    = -(1.0f / c);

        // ---- phase 1: wave grp evaluates row grp for its 64 columns ----
        {
            const int row = grp;
            const bool ok = cok && (row < B);
            const size_t off = (size_t)row * (size_t)P + (size_t)col;
            float z  = ok ? Z[off] : __int_as_float(0x7fc00000);  // NaN -> reject
            float Uv = ok ? U[off] : 1.0f;
            float tt = 1.0f + c * z;
            float V  = (tt * tt) * tt;               // (1+cZ)**3
            float rhs = ((0.5f * (z * z) + d) - d * V) + d * logf(V);
            bool acc = (z > ni) && (logf(Uv) < rhs);
            s_val[grp][lane] = d * V;
            unsigned long long bm = __ballot(acc);   // col-mask for this row
            if (lane == 0) s_rm[grp] = bm;
        }
        __syncthreads();

        // ---- phase 2: rebuild per-col 12-bit mask (LDS broadcasts) ----
        int mask = 0;
#pragma unroll
        for (int r = 0; r < ROWS; ++r)
            mask |= (int)((s_rm[r] >> lane) & 1ULL) << r;
        const int pc = __popc(mask);

        if (grp < KACC) {
            // wave grp stores theta row grp = (grp+1)-th accepted value
            if (cok && grp < pc) {
                int m = mask;
#pragma unroll
                for (int s = 0; s < KACC - 1; ++s)   // clear grp lowest set bits
                    if (s < grp) m &= m - 1;
                const int idx = __ffs(m) - 1;        // ascending row = stable order
                o_theta[(size_t)grp * (size_t)P + (size_t)col] = s_val[idx][lane];
            }
        } else if (grp == KACC) {
            if (cok) o_alpha[col] = alpha;
        }
        if (grp != 0) return;

        // ---- rare continuation (wave 0): cols with <K accepts in 12 rows ----
        const bool incomplete = cok && (pc < KACC);
        if (!__any(incomplete)) return;

        float th[KACC];
#pragma unroll
        for (int k = 0; k < KACC; ++k) th[k] = 0.0f;
        int cnt = (pc > KACC) ? KACC : pc;           // complete lanes: no-op

        for (int base = ROWS; base < B; base += 4) {
            float zv[4], wv[4];
#pragma unroll
            for (int i = 0; i < 4; ++i) {
                const int row = base + i;
                const size_t off = (size_t)row * (size_t)P + (size_t)col;
                const bool ok = cok && (row < B);
                zv[i] = ok ? Z[off] : __int_as_float(0x7fc00000);
                wv[i] = ok ? U[off] : 1.0f;
            }
#pragma unroll
            for (int i = 0; i < 4; ++i) {
                float z  = zv[i];
                float Uv = wv[i];
                float tt = 1.0f + c * z;
                float V  = (tt * tt) * tt;
                float rhs = ((0.5f * (z * z) + d) - d * V) + d * logf(V);
                bool acc = (z > ni) && (logf(Uv) < rhs) && (cnt < KACC);
                float val = d * V;
#pragma unroll
                for (int k = 0; k < KACC; ++k)
                    th[k] = (acc && cnt == k) ? val : th[k];
                cnt += acc ? 1 : 0;
            }
            if (__all(cnt >= KACC)) break;
        }

        if (incomplete) {
#pragma unroll
            for (int k = 0; k < KACC; ++k)           // rows pc..9 (rest done by waves)
                if (k >= pc) o_theta[(size_t)k * (size_t)P + (size_t)col] = th[k];
        }

    } else {
        // -------- GATE ROLE: one (k, p-chunk) slice per block (unchanged) --------
        const int gb  = bid - nbScan;
        const int k   = gb / perK;
        const int blk = gb - k * perK;
        const float SHIFT = 0.060606062f;            // BETA * (-GAMMA/ZETA)

        if (vec4) {
            const int P4 = P >> 2;
            const int i4 = blk * blockDim.x + threadIdx.x;
            if (i4 >= P4) return;

            const float4 u4  = reinterpret_cast<const float4*>(uu + (size_t)k * (size_t)P)[i4];
            const float4 la4 = reinterpret_cast<const float4*>(la)[i4];

            float4 z4;
            {
                const float* us = (const float*)&u4;
                const float* ls = (const float*)&la4;
                float* zs = (float*)&z4;
#pragma unroll
                for (int j = 0; j < 4; ++j) {
                    float x = ((__logf(us[j]) - __logf(1.0f - us[j])) + ls[j]) * 1.5f;
                    float s = 1.0f / (1.0f + __expf(-x));
                    float zz = 1.2f * s - 0.1f;
                    zs[j] = fminf(fmaxf(zz, 0.0f), 1.0f);
                }
            }
            reinterpret_cast<float4*>(o_z + (size_t)k * (size_t)P)[i4] = z4;

            if (k == 0) {
                const float* ls = (const float*)&la4;
                float4 zm4;
                float* zm = (float*)&zm4;
#pragma unroll
                for (int j = 0; j < 4; ++j)
                    zm[j] = 1.0f / (1.0f + __expf(-(ls[j] - SHIFT)));
                reinterpret_cast<float4*>(o_zmean)[i4]    = zm4;
                reinterpret_cast<float4*>(o_logalpha)[i4] = la4;
            }
        } else {
            const int p = blk * blockDim.x + threadIdx.x;
            if (p >= P) return;
            const float u = uu[(size_t)k * (size_t)P + (size_t)p];
            const float lalpha = la[p];
            float x = ((__logf(u) - __logf(1.0f - u)) + lalpha) * 1.5f;
            float s = 1.0f / (1.0f + __expf(-x));
            float zz = 1.2f * s - 0.1f;
            o_z[(size_t)k * (size_t)P + (size_t)p] = fminf(fmaxf(zz, 0.0f), 1.0f);
            if (k == 0) {
                o_zmean[p]    = 1.0f / (1.0f + __expf(-(lalpha - SHIFT)));
                o_logalpha[p] = lalpha;
            }
        }
    }
}

extern "C" void kernel_launch(void* const* d_in, const int* in_sizes, int n_in,
                              void* d_out, int out_size, void* d_ws, size_t ws_size,
                              hipStream_t stream) {
    const float* Z  = (const float*)d_in[0];
    const float* U  = (const float*)d_in[1];
    const float* uu = (const float*)d_in[2];
    const float* ga = (const float*)d_in[3];
    const float* la = (const float*)d_in[4];
    float* out = (float*)d_out;

    const int P = in_sizes[3];            // gamma_alpha is [P]
    const int B = in_sizes[0] / P;        // Z is [B,P]
    const int K = in_sizes[2] / P;        // u is [K,P]  (== KACC)

    const int block  = 768;               // 12 waves: rows 0..11 in parallel
    const int nbScan = (P + SC - 1) / SC; // 64 columns per scan block
    const int vec4   = (P % 4 == 0) ? 1 : 0;
    const int perK   = vec4 ? ((P / 4 + block - 1) / block)
                            : ((P + block - 1) / block);
    const int grid   = nbScan + K * perK; // scan blocks first (R5 ordering)
    sss_kernel<<<grid, block, 0, stream>>>(Z, U, uu, ga, la, out, P, B, nbScan, perK, vec4);
}

// Round 11
// 22.411 us; speedup vs baseline: 1.1268x; 1.1268x over previous
//
#include <hip/hip_runtime.h>
#include <math.h>

#define KACC 10
#define NRG 4      // waves per scan tile
#define RPG 3      // rows per wave -> 12 rows scanned up front
#define SCOLS 64   // columns per scan tile
#define GRID 2048  // persistent-ish grid (~resident capacity)

__global__ __launch_bounds__(256)
void sss_kernel(const float* __restrict__ Z, const float* __restrict__ U,
                const float* __restrict__ uu, const float* __restrict__ ga,
                const float* __restrict__ la, float* __restrict__ out,
                int P, int B, int nS, int nG, int Pq, int vec4, int nT)
{
#pragma clang fp contract(off)
    const size_t KP = (size_t)KACC * (size_t)P;
    float* o_z        = out;
    float* o_zmean    = out + KP;
    float* o_theta    = out + KP + (size_t)P;
    float* o_alpha    = out + 2 * KP + (size_t)P;
    float* o_logalpha = out + 2 * KP + 2 * (size_t)P;

    __shared__ float s_val[NRG * RPG][SCOLS];      // 3 KiB
    __shared__ int   s_msk[NRG][SCOLS];            // 1 KiB

    const int t    = threadIdx.x;
    const int lane = t & 63;
    const int rg   = t >> 6;
    const float SHIFT = 0.060606062f;              // BETA * (-GAMMA/ZETA)

    // period-5 work map: 3 scan tiles + 2 gate tiles (ratio ~3125:1954)
    for (int tile = blockIdx.x; tile < nT; tile += GRID) {
        const int q = tile / 5;
        const int r = tile - q * 5;

        if (r < 3) {
            // ================= SCAN TILE s =================
            const int s = q * 3 + r;
            if (s >= nS) continue;                 // block-uniform -> barrier-safe

            const int col = s * SCOLS + lane;
            const bool cok = (col < P);

            const float g = cok ? ga[col] : 1.0f;
            const float alpha = fmaxf(g, 0.0f) + 1.0f;   // relu + 1
            const float d     = alpha - (1.0f / 3.0f);
            const float c     = 1.0f / sqrtf(9.0f * d);
            const float ni    = -(1.0f / c);

            // phase 1: wave rg evaluates rows rg*RPG..+2 (loads batched up front)
            {
                float zv[RPG], wv[RPG];
#pragma unroll
                for (int j = 0; j < RPG; ++j) {
                    const int row = rg * RPG + j;
                    const size_t off = (size_t)row * (size_t)P + (size_t)col;
                    const bool ok = cok && (row < B);
                    zv[j] = ok ? Z[off] : __int_as_float(0x7fc00000);  // NaN -> reject
                    wv[j] = ok ? U[off] : 1.0f;
                }
                int m = 0;
#pragma unroll
                for (int j = 0; j < RPG; ++j) {
                    float z  = zv[j];
                    float Uv = wv[j];
                    float tt = 1.0f + c * z;
                    float V  = (tt * tt) * tt;           // (1+cZ)**3
                    float rhs = ((0.5f * (z * z) + d) - d * V) + d * logf(V);
                    bool acc = (z > ni) && (logf(Uv) < rhs);
                    m |= acc ? (1 << j) : 0;
                    s_val[rg * RPG + j][lane] = d * V;
                }
                s_msk[rg][lane] = m;
            }
            __syncthreads();

            const int mask = s_msk[0][lane]
                           | (s_msk[1][lane] << RPG)
                           | (s_msk[2][lane] << (2 * RPG))
                           | (s_msk[3][lane] << (3 * RPG));
            const int pc = __popc(mask);

            if (!__any(pc < KACC)) {
                // common path (~99%): tail split across the 4 waves
                int m = mask;
                const int skip = rg * RPG;               // 0,3,6,9
#pragma unroll
                for (int s2 = 0; s2 < (NRG - 1) * RPG; ++s2)
                    if (s2 < skip) m &= m - 1;
                const int kcnt = (rg == NRG - 1) ? (KACC - (NRG - 1) * RPG) : RPG;
#pragma unroll
                for (int j = 0; j < RPG; ++j) {
                    if (j < kcnt) {
                        const int idx = __ffs(m) - 1;    // ascending row = stable
                        const float v = s_val[idx][lane];
                        if (cok) o_theta[(size_t)(skip + j) * (size_t)P + (size_t)col] = v;
                        m &= m - 1;
                    }
                }
                if (rg == NRG - 1 && cok) o_alpha[col] = alpha;
            } else if (rg == 0) {
                // rare path: wave 0 does full extraction + continuation
                float th[KACC];
                {
                    int m = mask;
#pragma unroll
                    for (int k = 0; k < KACC; ++k) {
                        float v = 0.0f;
                        if (m) {
                            const int idx = __ffs(m) - 1;
                            v = s_val[idx][lane];
                            m &= m - 1;
                        }
                        th[k] = v;
                    }
                }
                int cnt = (pc > KACC) ? KACC : pc;

                if (cnt < KACC) {
                    for (int base = NRG * RPG; base < B; base += 4) {
                        float zv[4], wv[4];
#pragma unroll
                        for (int i = 0; i < 4; ++i) {
                            const int row = base + i;
                            const size_t off = (size_t)row * (size_t)P + (size_t)col;
                            const bool ok = cok && (row < B);
                            zv[i] = ok ? Z[off] : __int_as_float(0x7fc00000);
                            wv[i] = ok ? U[off] : 1.0f;
                        }
#pragma unroll
                        for (int i = 0; i < 4; ++i) {
                            float z  = zv[i];
                            float Uv = wv[i];
                            float tt = 1.0f + c * z;
                            float V  = (tt * tt) * tt;
                            float rhs = ((0.5f * (z * z) + d) - d * V) + d * logf(V);
                            bool acc = (z > ni) && (logf(Uv) < rhs) && (cnt < KACC);
                            float val = d * V;
#pragma unroll
                            for (int k = 0; k < KACC; ++k)
                                th[k] = (acc && cnt == k) ? val : th[k];
                            cnt += acc ? 1 : 0;
                        }
                        if (cnt >= KACC) break;
                    }
                }

                if (cok) {
#pragma unroll
                    for (int k = 0; k < KACC; ++k)
                        o_theta[(size_t)k * (size_t)P + (size_t)col] = th[k];
                    o_alpha[col] = alpha;
                }
            }
            __syncthreads();                       // LDS safe for next tile

        } else {
            // ================= GATE TILE g =================
            const int gidx = q * 2 + (r - 3);
            if (gidx >= nG) continue;

            if (vec4) {
                const int idx = gidx * 256 + t;    // flat f4 index into u[K][P/4]
                if (idx < KACC * Pq) {
                    const int k  = idx / Pq;
                    const int i4 = idx - k * Pq;

                    const float4 u4  = reinterpret_cast<const float4*>(uu)[idx];
                    const float4 la4 = reinterpret_cast<const float4*>(la)[i4];

                    float4 z4;
                    {
                        const float* us = (const float*)&u4;
                        const float* ls = (const float*)&la4;
                        float* zs = (float*)&z4;
#pragma unroll
                        for (int j = 0; j < 4; ++j) {
                            float x = ((__logf(us[j]) - __logf(1.0f - us[j])) + ls[j]) * 1.5f;
                            float sg = 1.0f / (1.0f + __expf(-x));
                            float zz = 1.2f * sg - 0.1f;
                            zs[j] = fminf(fmaxf(zz, 0.0f), 1.0f);
                        }
                    }
                    reinterpret_cast<float4*>(o_z)[idx] = z4;

                    if (k == 0) {
                        const float* ls = (const float*)&la4;
                        float4 zm4;
                        float* zm = (float*)&zm4;
#pragma unroll
                        for (int j = 0; j < 4; ++j)
                            zm[j] = 1.0f / (1.0f + __expf(-(ls[j] - SHIFT)));
                        reinterpret_cast<float4*>(o_zmean)[i4]    = zm4;
                        reinterpret_cast<float4*>(o_logalpha)[i4] = la4;
                    }
                }
            } else {
                const int idx = gidx * 256 + t;    // flat element index
                if (idx < KACC * P) {
                    const int k = idx / P;
                    const int p = idx - k * P;
                    const float u = uu[idx];
                    const float lalpha = la[p];
                    float x = ((__logf(u) - __logf(1.0f - u)) + lalpha) * 1.5f;
                    float sg = 1.0f / (1.0f + __expf(-x));
                    float zz = 1.2f * sg - 0.1f;
                    o_z[idx] = fminf(fmaxf(zz, 0.0f), 1.0f);
                    if (k == 0) {
                        o_zmean[p]    = 1.0f / (1.0f + __expf(-(lalpha - SHIFT)));
                        o_logalpha[p] = lalpha;
                    }
                }
            }
        }
    }
}

extern "C" void kernel_launch(void* const* d_in, const int* in_sizes, int n_in,
                              void* d_out, int out_size, void* d_ws, size_t ws_size,
                              hipStream_t stream) {
    const float* Z  = (const float*)d_in[0];
    const float* U  = (const float*)d_in[1];
    const float* uu = (const float*)d_in[2];
    const float* ga = (const float*)d_in[3];
    const float* la = (const float*)d_in[4];
    float* out = (float*)d_out;

    const int P = in_sizes[3];            // gamma_alpha is [P]
    const int B = in_sizes[0] / P;        // Z is [B,P]
    // K == KACC (u is [K,P])

    const int vec4 = (P % 4 == 0) ? 1 : 0;
    const int Pq   = P / 4;
    const int nS   = (P + SCOLS - 1) / SCOLS;                       // scan tiles
    const int nG   = vec4 ? (KACC * Pq + 255) / 256
                          : (KACC * P  + 255) / 256;                // gate tiles
    // period-5 map (3 scan : 2 gate); last t that touches a valid tile:
    const int tS = ((nS + 2) / 3) * 5;
    const int tG = ((nG + 1) / 2) * 5;
    const int nT = (tS > tG) ? tS : tG;

    sss_kernel<<<GRID, 256, 0, stream>>>(Z, U, uu, ga, la, out, P, B,
                                         nS, nG, Pq, vec4, nT);
}

// Round 12
// 18.830 us; speedup vs baseline: 1.3411x; 1.1901x over previous
//
#include <hip/hip_runtime.h>
#include <math.h>

#define KACC 10
#define NRG 4      // waves per block
#define RPG 3      // rows per wave -> 12 rows scanned up front
#define SCOLS 64   // columns per block
#define GE (SCOLS * KACC)   // 640 gate elements per block

// FUSED: one uniform block type does BOTH the Marsaglia-Tsang scan and the
// hard-concrete gate for the same 64 columns. One latency exposure per block.

__global__ __launch_bounds__(256)
void sss_kernel(const float* __restrict__ Z, const float* __restrict__ U,
                const float* __restrict__ uu, const float* __restrict__ ga,
                const float* __restrict__ la, float* __restrict__ out,
                int P, int B)
{
#pragma clang fp contract(off)
    const size_t KP = (size_t)KACC * (size_t)P;
    float* o_z        = out;
    float* o_zmean    = out + KP;
    float* o_theta    = out + KP + (size_t)P;
    float* o_alpha    = out + 2 * KP + (size_t)P;
    float* o_logalpha = out + 2 * KP + 2 * (size_t)P;

    __shared__ float s_val[NRG * RPG][SCOLS];      // 3 KiB
    __shared__ int   s_msk[NRG][SCOLS];            // 1 KiB

    const int bid  = blockIdx.x;
    const int t    = threadIdx.x;
    const int lane = t & 63;
    const int rg   = t >> 6;
    const int col0 = bid * SCOLS;
    const int col  = col0 + lane;
    const bool cok = (col < P);
    const float SHIFT = 0.060606062f;              // BETA * (-GAMMA/ZETA)

    // ---------- issue ALL loads up front (scan + gate share one latency) ----------
    const float g = cok ? ga[col] : 1.0f;
    float zv[RPG], wv[RPG];
#pragma unroll
    for (int j = 0; j < RPG; ++j) {
        const int row = rg * RPG + j;
        const size_t off = (size_t)row * (size_t)P + (size_t)col;
        const bool ok = cok && (row < B);
        zv[j] = ok ? Z[off] : __int_as_float(0x7fc00000);   // NaN -> reject
        wv[j] = ok ? U[off] : 1.0f;
    }
    // gate elements e = t, t+256, t+512 (<640): k = e/64, c = e%64
    float guv[3], glv[3];
    int   gk[3], gc[3];
    bool  gok[3];
#pragma unroll
    for (int i = 0; i < 3; ++i) {
        const int e = t + i * 256;
        gk[i]  = e >> 6;
        gc[i]  = e & 63;
        gok[i] = (e < GE) && (col0 + gc[i] < P);
        const size_t uoff = (size_t)gk[i] * (size_t)P + (size_t)(col0 + gc[i]);
        guv[i] = gok[i] ? uu[uoff] : 0.5f;
        glv[i] = gok[i] ? la[col0 + gc[i]] : 0.0f;
    }

    // ---------- scan accept math (precise logf, contract off) ----------
    const float alpha = fmaxf(g, 0.0f) + 1.0f;     // relu + 1
    const float d     = alpha - (1.0f / 3.0f);
    const float c     = 1.0f / sqrtf(9.0f * d);
    const float ni    = -(1.0f / c);
    {
        int m = 0;
#pragma unroll
        for (int j = 0; j < RPG; ++j) {
            float z  = zv[j];
            float Uv = wv[j];
            float tt = 1.0f + c * z;
            float V  = (tt * tt) * tt;             // (1+cZ)**3
            float rhs = ((0.5f * (z * z) + d) - d * V) + d * logf(V);
            bool acc = (z > ni) && (logf(Uv) < rhs);
            m |= acc ? (1 << j) : 0;
            s_val[rg * RPG + j][lane] = d * V;
        }
        s_msk[rg][lane] = m;
    }

    // ---------- gate math + stores (independent of barrier; fills latency shadow) ----------
#pragma unroll
    for (int i = 0; i < 3; ++i) {
        if (gok[i]) {
            float u = guv[i];
            float x = ((__logf(u) - __logf(1.0f - u)) + glv[i]) * 1.5f;
            float s = 1.0f / (1.0f + __expf(-x));
            float zz = 1.2f * s - 0.1f;
            o_z[(size_t)gk[i] * (size_t)P + (size_t)(col0 + gc[i])] =
                fminf(fmaxf(zz, 0.0f), 1.0f);
        }
    }
    if (t < SCOLS && cok) {                         // wave 0: zmean + logalpha
        const float l = la[col];
        o_zmean[col]    = 1.0f / (1.0f + __expf(-(l - SHIFT)));
        o_logalpha[col] = l;
    }

    __syncthreads();

    // ---------- extraction (R7 logic verbatim) ----------
    const int mask = s_msk[0][lane]
                   | (s_msk[1][lane] << RPG)
                   | (s_msk[2][lane] << (2 * RPG))
                   | (s_msk[3][lane] << (3 * RPG));
    const int pc = __popc(mask);

    if (!__any(pc < KACC)) {
        // common path (~99% of blocks): tail distributed across 4 waves
        int m = mask;
        const int skip = rg * RPG;                 // 0,3,6,9
#pragma unroll
        for (int s = 0; s < (NRG - 1) * RPG; ++s)
            if (s < skip) m &= m - 1;
        const int kcnt = (rg == NRG - 1) ? (KACC - (NRG - 1) * RPG) : RPG; // 3,3,3,1
#pragma unroll
        for (int j = 0; j < RPG; ++j) {
            if (j < kcnt) {
                const int idx = __ffs(m) - 1;      // ascending row = stable order
                const float v = s_val[idx][lane];
                if (cok) o_theta[(size_t)(skip + j) * (size_t)P + (size_t)col] = v;
                m &= m - 1;
            }
        }
        if (rg == NRG - 1 && cok) o_alpha[col] = alpha;
        return;
    }

    // rare path: wave 0 handles everything (incl. continuation)
    if (rg != 0) return;

    float th[KACC];
    {
        int m = mask;
#pragma unroll
        for (int k = 0; k < KACC; ++k) {
            float v = 0.0f;
            if (m) {
                const int idx = __ffs(m) - 1;
                v = s_val[idx][lane];
                m &= m - 1;
            }
            th[k] = v;
        }
    }
    int cnt = (pc > KACC) ? KACC : pc;

    if (cnt < KACC) {
        for (int base = NRG * RPG; base < B; base += 4) {
            float zv2[4], wv2[4];
#pragma unroll
            for (int i = 0; i < 4; ++i) {
                const int row = base + i;
                const size_t off = (size_t)row * (size_t)P + (size_t)col;
                const bool ok = cok && (row < B);
                zv2[i] = ok ? Z[off] : __int_as_float(0x7fc00000);
                wv2[i] = ok ? U[off] : 1.0f;
            }
#pragma unroll
            for (int i = 0; i < 4; ++i) {
                float z  = zv2[i];
                float Uv = wv2[i];
                float tt = 1.0f + c * z;
                float V  = (tt * tt) * tt;
                float rhs = ((0.5f * (z * z) + d) - d * V) + d * logf(V);
                bool acc = (z > ni) && (logf(Uv) < rhs) && (cnt < KACC);
                float val = d * V;
#pragma unroll
                for (int k = 0; k < KACC; ++k)
                    th[k] = (acc && cnt == k) ? val : th[k];
                cnt += acc ? 1 : 0;
            }
            if (cnt >= KACC) break;
        }
    }

    if (cok) {
#pragma unroll
        for (int k = 0; k < KACC; ++k)
            o_theta[(size_t)k * (size_t)P + (size_t)col] = th[k];
        o_alpha[col] = alpha;
    }
}

extern "C" void kernel_launch(void* const* d_in, const int* in_sizes, int n_in,
                              void* d_out, int out_size, void* d_ws, size_t ws_size,
                              hipStream_t stream) {
    const float* Z  = (const float*)d_in[0];
    const float* U  = (const float*)d_in[1];
    const float* uu = (const float*)d_in[2];
    const float* ga = (const float*)d_in[3];
    const float* la = (const float*)d_in[4];
    float* out = (float*)d_out;

    const int P = in_sizes[3];            // gamma_alpha is [P]
    const int B = in_sizes[0] / P;        // Z is [B,P]

    const int grid = (P + SCOLS - 1) / SCOLS;   // 3125 uniform fused blocks
    sss_kernel<<<grid, 256, 0, stream>>>(Z, U, uu, ga, la, out, P, B);
}

// Round 13
// 16.569 us; speedup vs baseline: 1.5241x; 1.1365x over previous
//
#include <hip/hip_runtime.h>
#include <math.h>

#define KACC 10
#define NRG 4      // parallel rowgroups per column
#define RPG 3      // rows per group -> 12 rows scanned up front
#define SCOLS 64   // columns per scan block

// R13 = R7 (best, 16.54us) + __launch_bounds__(256, 8):
// force <=64 VGPR so occupancy steps from 4 to 8 waves/SIMD (m69 step at 64).
// Rare continuation path may spill to scratch -- it runs on <9% of blocks.

__global__ __launch_bounds__(256, 8)
void sss_kernel(const float* __restrict__ Z, const float* __restrict__ U,
                const float* __restrict__ uu, const float* __restrict__ ga,
                const float* __restrict__ la, float* __restrict__ out,
                int P, int B, int nbScan, int perK, int vec4)
{
#pragma clang fp contract(off)
    const size_t KP = (size_t)KACC * (size_t)P;
    float* o_z        = out;
    float* o_zmean    = out + KP;
    float* o_theta    = out + KP + (size_t)P;
    float* o_alpha    = out + 2 * KP + (size_t)P;
    float* o_logalpha = out + 2 * KP + 2 * (size_t)P;

    const int bid = blockIdx.x;

    if (bid < nbScan) {
        // ---------------- SCAN ROLE: row-parallel Marsaglia-Tsang compaction ----------------
        __shared__ float s_val[NRG * RPG][SCOLS];
        __shared__ int   s_msk[NRG][SCOLS];

        const int t    = threadIdx.x;
        const int lane = t & (SCOLS - 1);
        const int rg   = t >> 6;
        const int col  = bid * SCOLS + lane;
        const bool cok = (col < P);

        const float g = cok ? ga[col] : 1.0f;
        const float alpha = fmaxf(g, 0.0f) + 1.0f;     // relu + 1
        const float d     = alpha - (1.0f / 3.0f);
        const float c     = 1.0f / sqrtf(9.0f * d);
        const float neg_inv_c = -(1.0f / c);

        // phase 1: rows rg*RPG .. rg*RPG+RPG-1, accept bit + candidate value
        {
            float zv[RPG], wv[RPG];
#pragma unroll
            for (int j = 0; j < RPG; ++j) {
                const int row = rg * RPG + j;
                const size_t off = (size_t)row * (size_t)P + (size_t)col;
                const bool ok = cok && (row < B);
                zv[j] = ok ? Z[off] : __int_as_float(0x7fc00000);  // NaN -> reject
                wv[j] = ok ? U[off] : 1.0f;
            }
            int m = 0;
#pragma unroll
            for (int j = 0; j < RPG; ++j) {
                float z  = zv[j];
                float Uv = wv[j];
                float tt = 1.0f + c * z;
                float V  = (tt * tt) * tt;             // (1+cZ)**3
                float rhs = ((0.5f * (z * z) + d) - d * V) + d * logf(V);
                bool acc = (z > neg_inv_c) && (logf(Uv) < rhs);
                m |= acc ? (1 << j) : 0;
                s_val[rg * RPG + j][lane] = d * V;
            }
            s_msk[rg][lane] = m;
        }
        __syncthreads();

        // all 4 waves rebuild the full 12-bit mask (same values in every wave)
        const int mask = s_msk[0][lane]
                       | (s_msk[1][lane] << RPG)
                       | (s_msk[2][lane] << (2 * RPG))
                       | (s_msk[3][lane] << (3 * RPG));
        const int pc = __popc(mask);

        if (!__any(pc < KACC)) {
            // ---- common path (~91% of blocks): tail distributed across 4 waves ----
            int m = mask;
            const int skip = rg * RPG;                 // 0,3,6,9
#pragma unroll
            for (int s = 0; s < (NRG - 1) * RPG; ++s)  // skip first `skip` set bits
                if (s < skip) m &= m - 1;
            const int kcnt = (rg == NRG - 1) ? (KACC - (NRG - 1) * RPG) : RPG; // 3,3,3,1
#pragma unroll
            for (int j = 0; j < RPG; ++j) {
                if (j < kcnt) {
                    const int idx = __ffs(m) - 1;      // next accepted row
                    const float v = s_val[idx][lane];
                    if (cok) o_theta[(size_t)(skip + j) * (size_t)P + (size_t)col] = v;
                    m &= m - 1;
                }
            }
            if (rg == NRG - 1 && cok) o_alpha[col] = alpha;
            return;
        }

        // ---- rare path: wave 0 handles everything (incl. continuation) ----
        if (rg != 0) return;

        float th[KACC];
        {
            int m = mask;
#pragma unroll
            for (int k = 0; k < KACC; ++k) {
                float v = 0.0f;
                if (m) {
                    const int idx = __ffs(m) - 1;
                    v = s_val[idx][lane];
                    m &= m - 1;
                }
                th[k] = v;
            }
        }
        int cnt = (pc > KACC) ? KACC : pc;

        if (cnt < KACC) {
            for (int base = NRG * RPG; base < B; base += 4) {
                float zv[4], wv[4];
#pragma unroll
                for (int i = 0; i < 4; ++i) {
                    const int row = base + i;
                    const size_t off = (size_t)row * (size_t)P + (size_t)col;
                    const bool ok = cok && (row < B);
                    zv[i] = ok ? Z[off] : __int_as_float(0x7fc00000);
                    wv[i] = ok ? U[off] : 1.0f;
                }
#pragma unroll
                for (int i = 0; i < 4; ++i) {
                    float z  = zv[i];
                    float Uv = wv[i];
                    float tt = 1.0f + c * z;
                    float V  = (tt * tt) * tt;
                    float rhs = ((0.5f * (z * z) + d) - d * V) + d * logf(V);
                    bool acc = (z > neg_inv_c) && (logf(Uv) < rhs) && (cnt < KACC);
                    float val = d * V;
#pragma unroll
                    for (int k = 0; k < KACC; ++k)
                        th[k] = (acc && cnt == k) ? val : th[k];
                    cnt += acc ? 1 : 0;
                }
                if (cnt >= KACC) break;
            }
        }

        if (cok) {
#pragma unroll
            for (int k = 0; k < KACC; ++k)
                o_theta[(size_t)k * (size_t)P + (size_t)col] = th[k];
            o_alpha[col] = alpha;
        }

    } else {
        // ---------------- GATE ROLE: one (k, p-chunk) slice per block ----------------
        const int gb  = bid - nbScan;
        const int k   = gb / perK;
        const int blk = gb - k * perK;
        const float SHIFT = 0.060606062f;              // BETA * (-GAMMA/ZETA)

        if (vec4) {
            const int P4 = P >> 2;
            const int i4 = blk * blockDim.x + threadIdx.x;
            if (i4 >= P4) return;

            const float4 u4  = reinterpret_cast<const float4*>(uu + (size_t)k * (size_t)P)[i4];
            const float4 la4 = reinterpret_cast<const float4*>(la)[i4];

            float4 z4;
            {
                const float* us = (const float*)&u4;
                const float* ls = (const float*)&la4;
                float* zs = (float*)&z4;
#pragma unroll
                for (int j = 0; j < 4; ++j) {
                    float x = ((__logf(us[j]) - __logf(1.0f - us[j])) + ls[j]) * 1.5f;
                    float s = 1.0f / (1.0f + __expf(-x));
                    float zz = 1.2f * s - 0.1f;
                    zs[j] = fminf(fmaxf(zz, 0.0f), 1.0f);
                }
            }
            reinterpret_cast<float4*>(o_z + (size_t)k * (size_t)P)[i4] = z4;

            if (k == 0) {
                const float* ls = (const float*)&la4;
                float4 zm4;
                float* zm = (float*)&zm4;
#pragma unroll
                for (int j = 0; j < 4; ++j)
                    zm[j] = 1.0f / (1.0f + __expf(-(ls[j] - SHIFT)));
                reinterpret_cast<float4*>(o_zmean)[i4]    = zm4;
                reinterpret_cast<float4*>(o_logalpha)[i4] = la4;
            }
        } else {
            const int p = blk * blockDim.x + threadIdx.x;
            if (p >= P) return;
            const float u = uu[(size_t)k * (size_t)P + (size_t)p];
            const float lalpha = la[p];
            float x = ((__logf(u) - __logf(1.0f - u)) + lalpha) * 1.5f;
            float s = 1.0f / (1.0f + __expf(-x));
            float zz = 1.2f * s - 0.1f;
            o_z[(size_t)k * (size_t)P + (size_t)p] = fminf(fmaxf(zz, 0.0f), 1.0f);
            if (k == 0) {
                o_zmean[p]    = 1.0f / (1.0f + __expf(-(lalpha - SHIFT)));
                o_logalpha[p] = lalpha;
            }
        }
    }
}

extern "C" void kernel_launch(void* const* d_in, const int* in_sizes, int n_in,
                              void* d_out, int out_size, void* d_ws, size_t ws_size,
                              hipStream_t stream) {
    const float* Z  = (const float*)d_in[0];
    const float* U  = (const float*)d_in[1];
    const float* uu = (const float*)d_in[2];
    const float* ga = (const float*)d_in[3];
    const float* la = (const float*)d_in[4];
    float* out = (float*)d_out;

    const int P = in_sizes[3];            // gamma_alpha is [P]
    const int B = in_sizes[0] / P;        // Z is [B,P]
    const int K = in_sizes[2] / P;        // u is [K,P]  (== KACC)

    const int block  = 256;
    const int nbScan = (P + SCOLS - 1) / SCOLS;        // 64 columns per scan block
    const int vec4   = (P % 4 == 0) ? 1 : 0;
    const int perK   = vec4 ? ((P / 4 + block - 1) / block)
                            : ((P + block - 1) / block);
    const int grid   = nbScan + K * perK;              // scan blocks first (R5 ordering)
    sss_kernel<<<grid, block, 0, stream>>>(Z, U, uu, ga, la, out, P, B, nbScan, perK, vec4);
}